// Round 8
// baseline (178.941 us; speedup 1.0000x reference)
//
#include <hip/hip_runtime.h>
#include <hip/hip_fp8.h>

typedef float    f32x16 __attribute__((ext_vector_type(16)));
typedef _Float16 f16x8  __attribute__((ext_vector_type(8)));

#define NWAVES 4
#define TPW 4
#define TILES_PER_BLOCK (NWAVES * TPW)

// ---- fp8 e4m3 helpers (HW cvt on gfx950; encode/decode self-consistent) ----
__device__ __forceinline__ uint32_t enc4_fp8(float a, float b, float c, float d) {
#if __has_builtin(__builtin_amdgcn_cvt_pk_fp8_f32)
    int w = __builtin_amdgcn_cvt_pk_fp8_f32(a, b, 0, false);
    w     = __builtin_amdgcn_cvt_pk_fp8_f32(c, d, w, true);
    return (uint32_t)w;
#else
    __hip_fp8_e4m3 e0(a), e1(b), e2(c), e3(d);
    return (uint32_t)e0.__x | ((uint32_t)e1.__x << 8) |
           ((uint32_t)e2.__x << 16) | ((uint32_t)e3.__x << 24);
#endif
}

__device__ __forceinline__ f16x8 dec8_fp8(uint2 u) {
    f16x8 v;
#if __has_builtin(__builtin_amdgcn_cvt_f32_fp8)
    {
        const float f0 = __builtin_amdgcn_cvt_f32_fp8((int)u.x, 0);
        const float f1 = __builtin_amdgcn_cvt_f32_fp8((int)u.x, 1);
        const float f2 = __builtin_amdgcn_cvt_f32_fp8((int)u.x, 2);
        const float f3 = __builtin_amdgcn_cvt_f32_fp8((int)u.x, 3);
        const auto h01 = __builtin_amdgcn_cvt_pkrtz(f0, f1);  // exact: e4m3 subset of f16
        const auto h23 = __builtin_amdgcn_cvt_pkrtz(f2, f3);
        v[0] = h01[0]; v[1] = h01[1]; v[2] = h23[0]; v[3] = h23[1];
    }
    {
        const float f0 = __builtin_amdgcn_cvt_f32_fp8((int)u.y, 0);
        const float f1 = __builtin_amdgcn_cvt_f32_fp8((int)u.y, 1);
        const float f2 = __builtin_amdgcn_cvt_f32_fp8((int)u.y, 2);
        const float f3 = __builtin_amdgcn_cvt_f32_fp8((int)u.y, 3);
        const auto h01 = __builtin_amdgcn_cvt_pkrtz(f0, f1);
        const auto h23 = __builtin_amdgcn_cvt_pkrtz(f2, f3);
        v[4] = h01[0]; v[5] = h01[1]; v[6] = h23[0]; v[7] = h23[1];
    }
#else
    union { uint2 w; unsigned char b[8]; } cc; cc.w = u;
    #pragma unroll
    for (int j = 0; j < 8; ++j) {
        __hip_fp8_e4m3 t; t.__x = cc.b[j];
        v[j] = (_Float16)(float)t;
    }
#endif
    return v;
}

// ---------------- prep: f32 node tables -> fp8 tables in d_ws ----------------
__global__ __launch_bounds__(256) void prep_fp8(
    const float* __restrict__ zi, const float* __restrict__ zj,
    uint2* __restrict__ zif8, uint2* __restrict__ zjf8, const int nChunkPer)
{
    const int stride = gridDim.x * blockDim.x;
    for (int c = blockIdx.x * blockDim.x + threadIdx.x; c < 2 * nChunkPer; c += stride) {
        const float* s;
        uint2* d;
        int cc;
        if (c < nChunkPer) { cc = c; s = zi + (size_t)cc * 8; d = zif8 + cc; }
        else { cc = c - nChunkPer; s = zj + (size_t)cc * 8; d = zjf8 + cc; }
        const float4 a0 = *reinterpret_cast<const float4*>(s);
        const float4 a1 = *reinterpret_cast<const float4*>(s + 4);
        uint2 w;
        w.x = enc4_fp8(a0.x, a0.y, a0.z, a0.w);
        w.y = enc4_fp8(a1.x, a1.y, a1.z, a1.w);
        *d = w;
    }
}

// ---------------- main ----------------
// Per edge: raw = concat(zi[src] (64), zj[dst] (64));
// hid = relu(raw @ W1^T + b1) [128]; score = sigmoid(hid . W3 + b3).
// neg_score == pos_score (source bug: both scored from raw_pos).
template<bool FP8>
__global__ __launch_bounds__(256, 4) void graphlp_mfma(
    const float* __restrict__ zi, const float* __restrict__ zj,
    const unsigned char* __restrict__ zif8, const unsigned char* __restrict__ zjf8,
    const float* __restrict__ W1, const float* __restrict__ b1p,
    const float* __restrict__ W3, const float* __restrict__ b3p,
    const int* __restrict__ psrc, const int* __restrict__ pdst,
    float* __restrict__ out, const int nEdges, const int nTiles)
{
    // W1 as f16, swizzled: byte = row*256 + ((k*2) ^ ((row&7)<<4)); 32 KiB
    __shared__ uint4 w1s[2048];
    char* lds = reinterpret_cast<char*>(w1s);
    const int tid = threadIdx.x;

    #pragma unroll
    for (int i = 0; i < 8; ++i) {
        const int ch  = tid + i * 256;   // 2048 chunks of 8 f32
        const int row = ch >> 4;         // 0..127 (hidden unit n)
        const int kg  = ch & 15;         // 8-wide k group
        const float* s = W1 + row * 128 + kg * 8;
        const float4 a0 = *reinterpret_cast<const float4*>(s);
        const float4 a1 = *reinterpret_cast<const float4*>(s + 4);
        f16x8 v;
        v[0]=(_Float16)a0.x; v[1]=(_Float16)a0.y; v[2]=(_Float16)a0.z; v[3]=(_Float16)a0.w;
        v[4]=(_Float16)a1.x; v[5]=(_Float16)a1.y; v[6]=(_Float16)a1.z; v[7]=(_Float16)a1.w;
        const int off = row * 256 + ((kg * 16) ^ ((row & 7) << 4));
        *reinterpret_cast<f16x8*>(lds + off) = v;
    }
    __syncthreads();

    const int lane = tid & 63;
    const int wav  = tid >> 6;
    const int lr   = lane & 31;   // edge-row / n-col within 32
    const int lq   = lane >> 5;   // k-half selector

    float b1v[4], w3v[4];
    #pragma unroll
    for (int nb = 0; nb < 4; ++nb) {
        b1v[nb] = b1p[nb * 32 + lr];
        w3v[nb] = W3[nb * 32 + lr];
    }
    const float b3 = b3p[0];

    const int gbase = blockIdx.x * TILES_PER_BLOCK + wav;

    // ---- pipeline prologue: idx(t0), idx(t1); raw fp8 gather for t0 ----
    uint2 px[8];            // current tile's raw fp8 A data (16 VGPR only)
    int si1 = 0, di1 = 0;
    #pragma unroll
    for (int kk = 0; kk < 8; ++kk) { px[kk].x = 0u; px[kk].y = 0u; }
    if constexpr (FP8) {
        int si0 = 0, di0 = 0;
        if (gbase < nTiles) {
            const int e = min(gbase * 32 + lr, nEdges - 1);
            si0 = psrc[e]; di0 = pdst[e];
        }
        const int gB = gbase + NWAVES;
        if (gB < nTiles) {
            const int e = min(gB * 32 + lr, nEdges - 1);
            si1 = psrc[e]; di1 = pdst[e];
        }
        if (gbase < nTiles) {
            const unsigned char* sp = zif8 + (size_t)si0 * 64;
            const unsigned char* dp = zjf8 + (size_t)di0 * 64;
            #pragma unroll
            for (int kk = 0; kk < 4; ++kk) {
                px[kk]     = *reinterpret_cast<const uint2*>(sp + kk * 16 + lq * 8);
                px[kk + 4] = *reinterpret_cast<const uint2*>(dp + kk * 16 + lq * 8);
            }
        }
    } else {
        if (gbase < nTiles) {
            const int e = min(gbase * 32 + lr, nEdges - 1);
            si1 = psrc[e]; di1 = pdst[e];   // f32 path: si1/di1 = current idx
        }
    }

    #pragma unroll
    for (int t = 0; t < TPW; ++t) {
        const int g = gbase + t * NWAVES;
        if (g >= nTiles) break;          // wave-uniform

        f16x8 afrag[8];
        uint2 pn[8];
        int si2 = 0, di2 = 0;

        if constexpr (FP8) {
            // issue t+1 raw gathers first (fly under convert+MFMA+epilogue)
            const bool havnext = (t + 1 < TPW) && (g + NWAVES < nTiles);
            #pragma unroll
            for (int kk = 0; kk < 8; ++kk) { pn[kk].x = 0u; pn[kk].y = 0u; }
            if (havnext) {
                const unsigned char* sp = zif8 + (size_t)si1 * 64;
                const unsigned char* dp = zjf8 + (size_t)di1 * 64;
                #pragma unroll
                for (int kk = 0; kk < 4; ++kk) {
                    pn[kk]     = *reinterpret_cast<const uint2*>(sp + kk * 16 + lq * 8);
                    pn[kk + 4] = *reinterpret_cast<const uint2*>(dp + kk * 16 + lq * 8);
                }
            }
            // prefetch indices for t+2
            if (t + 2 < TPW) {
                const int g2 = g + 2 * NWAVES;
                if (g2 < nTiles) {
                    const int e2 = min(g2 * 32 + lr, nEdges - 1);
                    si2 = psrc[e2]; di2 = pdst[e2];
                }
            }
            // decode current tile fp8 -> f16 fragments
            #pragma unroll
            for (int kk = 0; kk < 8; ++kk) afrag[kk] = dec8_fp8(px[kk]);
        } else {
            // f32 fallback: gather + convert inline (r1-proven)
            const float* sp = zi + (size_t)si1 * 64;
            const float* dp = zj + (size_t)di1 * 64;
            #pragma unroll
            for (int kk = 0; kk < 8; ++kk) {
                const int kb = kk * 16 + lq * 8;
                const float* p = (kk < 4) ? (sp + kb) : (dp + kb - 64);
                const float4 a0 = *reinterpret_cast<const float4*>(p);
                const float4 a1 = *reinterpret_cast<const float4*>(p + 4);
                f16x8 v;
                v[0]=(_Float16)a0.x; v[1]=(_Float16)a0.y; v[2]=(_Float16)a0.z; v[3]=(_Float16)a0.w;
                v[4]=(_Float16)a1.x; v[5]=(_Float16)a1.y; v[6]=(_Float16)a1.z; v[7]=(_Float16)a1.w;
                afrag[kk] = v;
            }
            if (t + 1 < TPW) {
                const int gn = g + NWAVES;
                if (gn < nTiles) {
                    const int en = min(gn * 32 + lr, nEdges - 1);
                    si2 = psrc[en]; di2 = pdst[en];
                }
            }
        }

        float pr[16];
        #pragma unroll
        for (int r = 0; r < 16; ++r) pr[r] = 0.0f;

        // nb processed in pairs: 2x16 acc regs live instead of 4x16
        #pragma unroll
        for (int nbp = 0; nbp < 2; ++nbp) {
            const float bb0 = b1v[2*nbp], bb1 = b1v[2*nbp + 1];
            f32x16 acc0, acc1;
            #pragma unroll
            for (int r = 0; r < 16; ++r) { acc0[r] = bb0; acc1[r] = bb1; }  // bias via C-in
            const int n0 = (2*nbp)     * 32 + lr;            // W1 rows
            const int n1 = (2*nbp + 1) * 32 + lr;
            __builtin_amdgcn_s_setprio(1);
            #pragma unroll
            for (int kk = 0; kk < 8; ++kk) {
                const int kx = kk * 32 + lq * 16;
                const f16x8 bf0 = *reinterpret_cast<const f16x8*>(
                    lds + n0 * 256 + (kx ^ ((n0 & 7) << 4)));
                const f16x8 bf1 = *reinterpret_cast<const f16x8*>(
                    lds + n1 * 256 + (kx ^ ((n1 & 7) << 4)));
                acc0 = __builtin_amdgcn_mfma_f32_32x32x16_f16(afrag[kk], bf0, acc0, 0, 0, 0);
                acc1 = __builtin_amdgcn_mfma_f32_32x32x16_f16(afrag[kk], bf1, acc1, 0, 0, 0);
            }
            __builtin_amdgcn_s_setprio(0);
            const float ww0 = w3v[2*nbp], ww1 = w3v[2*nbp + 1];
            #pragma unroll
            for (int r = 0; r < 16; ++r) {
                pr[r] = fmaf(fmaxf(acc0[r], 0.0f), ww0, pr[r]);
                pr[r] = fmaf(fmaxf(acc1[r], 0.0f), ww1, pr[r]);
            }
        }

        // fold-reduce over the 32 n-lanes: halve reg count each stage
        float p8[8];
        #pragma unroll
        for (int r = 0; r < 8; ++r) {
            const float lo = pr[r], hi = pr[r + 8];
            const float sent = (lane & 1) ? lo : hi;
            const float got  = __shfl_xor(sent, 1);
            p8[r] = ((lane & 1) ? hi : lo) + got;
        }
        float p4[4];
        #pragma unroll
        for (int r = 0; r < 4; ++r) {
            const float lo = p8[r], hi = p8[r + 4];
            const float sent = (lane & 2) ? lo : hi;
            const float got  = __shfl_xor(sent, 2);
            p4[r] = ((lane & 2) ? hi : lo) + got;
        }
        float p2[2];
        #pragma unroll
        for (int r = 0; r < 2; ++r) {
            const float lo = p4[r], hi = p4[r + 2];
            const float sent = (lane & 4) ? lo : hi;
            const float got  = __shfl_xor(sent, 4);
            p2[r] = ((lane & 4) ? hi : lo) + got;
        }
        float p1;
        {
            const float lo = p2[0], hi = p2[1];
            const float sent = (lane & 8) ? lo : hi;
            const float got  = __shfl_xor(sent, 8);
            p1 = ((lane & 8) ? hi : lo) + got;
        }
        p1 += __shfl_xor(p1, 16);

        // lane -> original reg index rid; edge m = (rid&3) + 8*(rid>>2) + 4*lq
        const int rid = 8 * (lane & 1) + 4 * ((lane >> 1) & 1)
                      + 2 * ((lane >> 2) & 1) + ((lane >> 3) & 1);
        const int m  = (rid & 3) + 8 * (rid >> 2) + 4 * lq;
        const int eo = g * 32 + m;
        if (eo < nEdges) {
            const float sc = 1.0f / (1.0f + __expf(-(p1 + b3)));
            if (lane & 16) out[nEdges + eo] = sc;   // neg_score (== pos)
            else           out[eo] = sc;            // pos_score
        }

        // rotate pipeline state
        if constexpr (FP8) {
            #pragma unroll
            for (int kk = 0; kk < 8; ++kk) px[kk] = pn[kk];
        }
        si1 = si2; di1 = di2;
    }
}

extern "C" void kernel_launch(void* const* d_in, const int* in_sizes, int n_in,
                              void* d_out, int out_size, void* d_ws, size_t ws_size,
                              hipStream_t stream)
{
    const float* zi = (const float*)d_in[0];
    const float* zj = (const float*)d_in[1];
    // d_in[2] = zn  (unused: neg path is dead code in the reference)
    const float* W1 = (const float*)d_in[3];
    const float* b1 = (const float*)d_in[4];
    const float* W3 = (const float*)d_in[5];
    const float* b3 = (const float*)d_in[6];
    const int* psrc = (const int*)d_in[7];
    const int* pdst = (const int*)d_in[8];
    float* out = (float*)d_out;

    const int nEdges = in_sizes[7];
    const int nNodesI = in_sizes[0] / 64;   // zi rows
    const int nNodesJ = in_sizes[1] / 64;   // zj rows
    const int nTiles = (nEdges + 31) / 32;
    const int nBlocks = (nTiles + TILES_PER_BLOCK - 1) / TILES_PER_BLOCK;

    const size_t bytesI = (size_t)nNodesI * 64;   // 1 byte per element
    const size_t bytesJ = (size_t)nNodesJ * 64;
    const bool useF8 = (ws_size >= bytesI + bytesJ);

    if (useF8) {
        unsigned char* zif8 = (unsigned char*)d_ws;
        unsigned char* zjf8 = (unsigned char*)d_ws + bytesI;
        const int nChunkPer = nNodesI * 64 / 8;
        hipLaunchKernelGGL(prep_fp8, dim3(2048), dim3(256), 0, stream,
                           zi, zj, (uint2*)zif8, (uint2*)zjf8, nChunkPer);
        hipLaunchKernelGGL((graphlp_mfma<true>), dim3(nBlocks), dim3(256), 0, stream,
                           zi, zj, zif8, zjf8, W1, b1, W3, b3, psrc, pdst,
                           out, nEdges, nTiles);
    } else {
        hipLaunchKernelGGL((graphlp_mfma<false>), dim3(nBlocks), dim3(256), 0, stream,
                           zi, zj, (const unsigned char*)nullptr, (const unsigned char*)nullptr,
                           W1, b1, W3, b3, psrc, pdst, out, nEdges, nTiles);
    }
}

// Round 9
// 72.356 us; speedup vs baseline: 2.4731x; 2.4731x over previous
//
#include <hip/hip_runtime.h>
#include <hip/hip_fp8.h>

typedef float    f32x16 __attribute__((ext_vector_type(16)));
typedef _Float16 f16x8  __attribute__((ext_vector_type(8)));

#define NWAVES 4
#define TPW 4
#define TILES_PER_BLOCK (NWAVES * TPW)

// ---- fp8 e4m3 helpers (HW cvt on gfx950; encode/decode self-consistent) ----
__device__ __forceinline__ uint32_t enc4_fp8(float a, float b, float c, float d) {
#if __has_builtin(__builtin_amdgcn_cvt_pk_fp8_f32)
    int w = __builtin_amdgcn_cvt_pk_fp8_f32(a, b, 0, false);
    w     = __builtin_amdgcn_cvt_pk_fp8_f32(c, d, w, true);
    return (uint32_t)w;
#else
    __hip_fp8_e4m3 e0(a), e1(b), e2(c), e3(d);
    return (uint32_t)e0.__x | ((uint32_t)e1.__x << 8) |
           ((uint32_t)e2.__x << 16) | ((uint32_t)e3.__x << 24);
#endif
}

__device__ __forceinline__ void dec4_fp8(uint32_t w, _Float16* o) {
#if __has_builtin(__builtin_amdgcn_cvt_pk_f32_fp8)
    const auto f01 = __builtin_amdgcn_cvt_pk_f32_fp8((int)w, false); // bytes 0,1
    const auto f23 = __builtin_amdgcn_cvt_pk_f32_fp8((int)w, true);  // bytes 2,3
    const auto h01 = __builtin_amdgcn_cvt_pkrtz(f01[0], f01[1]);     // exact: e4m3 ⊂ f16
    const auto h23 = __builtin_amdgcn_cvt_pkrtz(f23[0], f23[1]);
    o[0] = h01[0]; o[1] = h01[1]; o[2] = h23[0]; o[3] = h23[1];
#else
    #pragma unroll
    for (int j = 0; j < 4; ++j) {
        __hip_fp8_e4m3 t; t.__x = (unsigned char)(w >> (8 * j));
        o[j] = (_Float16)(float)t;
    }
#endif
}

__device__ __forceinline__ f16x8 dec8_fp8(uint2 u) {
    f16x8 v;
    _Float16 tmp[8];
    dec4_fp8(u.x, tmp);
    dec4_fp8(u.y, tmp + 4);
    #pragma unroll
    for (int j = 0; j < 8; ++j) v[j] = tmp[j];
    return v;
}

// ---------------- prep: f32 node tables -> fp8 tables in d_ws ----------------
__global__ __launch_bounds__(256) void prep_fp8(
    const float* __restrict__ zi, const float* __restrict__ zj,
    uint2* __restrict__ zif8, uint2* __restrict__ zjf8, const int nChunkPer)
{
    const int stride = gridDim.x * blockDim.x;
    for (int c = blockIdx.x * blockDim.x + threadIdx.x; c < 2 * nChunkPer; c += stride) {
        const float* s;
        uint2* d;
        int cc;
        if (c < nChunkPer) { cc = c; s = zi + (size_t)cc * 8; d = zif8 + cc; }
        else { cc = c - nChunkPer; s = zj + (size_t)cc * 8; d = zjf8 + cc; }
        const float4 a0 = *reinterpret_cast<const float4*>(s);
        const float4 a1 = *reinterpret_cast<const float4*>(s + 4);
        uint2 w;
        w.x = enc4_fp8(a0.x, a0.y, a0.z, a0.w);
        w.y = enc4_fp8(a1.x, a1.y, a1.z, a1.w);
        *d = w;
    }
}

// ---------------- main ----------------
// Per edge: raw = concat(zi[src] (64), zj[dst] (64));
// hid = relu(raw @ W1^T + b1) [128]; score = sigmoid(hid . W3 + b3).
// neg_score == pos_score (source bug: both scored from raw_pos).
// r4 structure exactly (60.5 us proven): depth-1 idx prefetch, no A-prefetch,
// no launch_bounds min-wave forcing (r8's (256,4) caused scratch spills).
template<bool FP8>
__global__ __launch_bounds__(256) void graphlp_mfma(
    const float* __restrict__ zi, const float* __restrict__ zj,
    const unsigned char* __restrict__ zif8, const unsigned char* __restrict__ zjf8,
    const float* __restrict__ W1, const float* __restrict__ b1p,
    const float* __restrict__ W3, const float* __restrict__ b3p,
    const int* __restrict__ psrc, const int* __restrict__ pdst,
    float* __restrict__ out, const int nEdges, const int nTiles)
{
    // W1 as f16, swizzled: byte = row*256 + ((k*2) ^ ((row&7)<<4)); 32 KiB
    __shared__ uint4 w1s[2048];
    char* lds = reinterpret_cast<char*>(w1s);
    const int tid = threadIdx.x;

    #pragma unroll
    for (int i = 0; i < 8; ++i) {
        const int ch  = tid + i * 256;   // 2048 chunks of 8 f32
        const int row = ch >> 4;         // 0..127 (hidden unit n)
        const int kg  = ch & 15;         // 8-wide k group
        const float* s = W1 + row * 128 + kg * 8;
        const float4 a0 = *reinterpret_cast<const float4*>(s);
        const float4 a1 = *reinterpret_cast<const float4*>(s + 4);
        f16x8 v;
        v[0]=(_Float16)a0.x; v[1]=(_Float16)a0.y; v[2]=(_Float16)a0.z; v[3]=(_Float16)a0.w;
        v[4]=(_Float16)a1.x; v[5]=(_Float16)a1.y; v[6]=(_Float16)a1.z; v[7]=(_Float16)a1.w;
        const int off = row * 256 + ((kg * 16) ^ ((row & 7) << 4));
        *reinterpret_cast<f16x8*>(lds + off) = v;
    }
    __syncthreads();

    const int lane = tid & 63;
    const int wav  = tid >> 6;
    const int lr   = lane & 31;   // edge-row / n-col within 32
    const int lq   = lane >> 5;   // k-half selector

    float b1v[4], w3v[4];
    #pragma unroll
    for (int nb = 0; nb < 4; ++nb) {
        b1v[nb] = b1p[nb * 32 + lr];
        w3v[nb] = W3[nb * 32 + lr];
    }
    const float b3 = b3p[0];

    // consecutive tiles per block (r4 mapping; grid-stride regressed r2)
    int si = 0, di = 0;
    {
        const int g0 = blockIdx.x * TILES_PER_BLOCK + wav;  // t=0 tile
        if (g0 < nTiles) {
            const int e = min(g0 * 32 + lr, nEdges - 1);
            si = psrc[e]; di = pdst[e];
        }
    }

    #pragma unroll
    for (int t = 0; t < TPW; ++t) {
        const int g = blockIdx.x * TILES_PER_BLOCK + t * NWAVES + wav;
        if (g >= nTiles) break;          // wave-uniform

        // prefetch next tile's indices (hide idx->gather dependency)
        int si_n = 0, di_n = 0;
        if (t + 1 < TPW) {
            const int gn = g + NWAVES;
            if (gn < nTiles) {
                const int en = min(gn * 32 + lr, nEdges - 1);
                si_n = psrc[en]; di_n = pdst[en];
            }
        }

        // A fragments: lane holds raw[lr][kk*16 + lq*8 .. +8)
        f16x8 afrag[8];
        if constexpr (FP8) {
            const unsigned char* __restrict__ sp = zif8 + (size_t)si * 64;
            const unsigned char* __restrict__ dp = zjf8 + (size_t)di * 64;
            uint2 px[8];
            #pragma unroll
            for (int kk = 0; kk < 4; ++kk) {
                px[kk]     = *reinterpret_cast<const uint2*>(sp + kk * 16 + lq * 8);
                px[kk + 4] = *reinterpret_cast<const uint2*>(dp + kk * 16 + lq * 8);
            }
            #pragma unroll
            for (int kk = 0; kk < 8; ++kk) afrag[kk] = dec8_fp8(px[kk]);
        } else {
            const float* __restrict__ sp = zi + (size_t)si * 64;
            const float* __restrict__ dp = zj + (size_t)di * 64;
            #pragma unroll
            for (int kk = 0; kk < 8; ++kk) {
                const int kb = kk * 16 + lq * 8;             // 0..120, step 8
                const float* p = (kk < 4) ? (sp + kb) : (dp + kb - 64);
                const float4 a0 = *reinterpret_cast<const float4*>(p);
                const float4 a1 = *reinterpret_cast<const float4*>(p + 4);
                f16x8 v;
                v[0]=(_Float16)a0.x; v[1]=(_Float16)a0.y; v[2]=(_Float16)a0.z; v[3]=(_Float16)a0.w;
                v[4]=(_Float16)a1.x; v[5]=(_Float16)a1.y; v[6]=(_Float16)a1.z; v[7]=(_Float16)a1.w;
                afrag[kk] = v;
            }
        }

        float pr[16];
        #pragma unroll
        for (int r = 0; r < 16; ++r) pr[r] = 0.0f;

        // nb processed in pairs: 2x16 acc regs live instead of 4x16
        #pragma unroll
        for (int nbp = 0; nbp < 2; ++nbp) {
            const float bb0 = b1v[2*nbp], bb1 = b1v[2*nbp + 1];
            f32x16 acc0, acc1;
            #pragma unroll
            for (int r = 0; r < 16; ++r) { acc0[r] = bb0; acc1[r] = bb1; }  // bias via C-in
            const int n0 = (2*nbp)     * 32 + lr;            // W1 rows
            const int n1 = (2*nbp + 1) * 32 + lr;
            __builtin_amdgcn_s_setprio(1);
            #pragma unroll
            for (int kk = 0; kk < 8; ++kk) {
                const int kx = kk * 32 + lq * 16;
                const f16x8 bf0 = *reinterpret_cast<const f16x8*>(
                    lds + n0 * 256 + (kx ^ ((n0 & 7) << 4)));
                const f16x8 bf1 = *reinterpret_cast<const f16x8*>(
                    lds + n1 * 256 + (kx ^ ((n1 & 7) << 4)));
                acc0 = __builtin_amdgcn_mfma_f32_32x32x16_f16(afrag[kk], bf0, acc0, 0, 0, 0);
                acc1 = __builtin_amdgcn_mfma_f32_32x32x16_f16(afrag[kk], bf1, acc1, 0, 0, 0);
            }
            __builtin_amdgcn_s_setprio(0);
            const float ww0 = w3v[2*nbp], ww1 = w3v[2*nbp + 1];
            #pragma unroll
            for (int r = 0; r < 16; ++r) {
                pr[r] = fmaf(fmaxf(acc0[r], 0.0f), ww0, pr[r]);
                pr[r] = fmaf(fmaxf(acc1[r], 0.0f), ww1, pr[r]);
            }
        }

        // fold-reduce over the 32 n-lanes: halve reg count each stage
        float p8[8];
        #pragma unroll
        for (int r = 0; r < 8; ++r) {
            const float lo = pr[r], hi = pr[r + 8];
            const float sent = (lane & 1) ? lo : hi;
            const float got  = __shfl_xor(sent, 1);
            p8[r] = ((lane & 1) ? hi : lo) + got;
        }
        float p4[4];
        #pragma unroll
        for (int r = 0; r < 4; ++r) {
            const float lo = p8[r], hi = p8[r + 4];
            const float sent = (lane & 2) ? lo : hi;
            const float got  = __shfl_xor(sent, 2);
            p4[r] = ((lane & 2) ? hi : lo) + got;
        }
        float p2[2];
        #pragma unroll
        for (int r = 0; r < 2; ++r) {
            const float lo = p4[r], hi = p4[r + 2];
            const float sent = (lane & 4) ? lo : hi;
            const float got  = __shfl_xor(sent, 4);
            p2[r] = ((lane & 4) ? hi : lo) + got;
        }
        float p1;
        {
            const float lo = p2[0], hi = p2[1];
            const float sent = (lane & 8) ? lo : hi;
            const float got  = __shfl_xor(sent, 8);
            p1 = ((lane & 8) ? hi : lo) + got;
        }
        p1 += __shfl_xor(p1, 16);

        // lane -> original reg index rid; edge m = (rid&3) + 8*(rid>>2) + 4*lq
        const int rid = 8 * (lane & 1) + 4 * ((lane >> 1) & 1)
                      + 2 * ((lane >> 2) & 1) + ((lane >> 3) & 1);
        const int m  = (rid & 3) + 8 * (rid >> 2) + 4 * lq;
        const int eo = g * 32 + m;
        if (eo < nEdges) {
            const float sc = 1.0f / (1.0f + __expf(-(p1 + b3)));
            if (lane & 16) out[nEdges + eo] = sc;   // neg_score (== pos)
            else           out[eo] = sc;            // pos_score
        }

        si = si_n; di = di_n;
    }
}

extern "C" void kernel_launch(void* const* d_in, const int* in_sizes, int n_in,
                              void* d_out, int out_size, void* d_ws, size_t ws_size,
                              hipStream_t stream)
{
    const float* zi = (const float*)d_in[0];
    const float* zj = (const float*)d_in[1];
    // d_in[2] = zn  (unused: neg path is dead code in the reference)
    const float* W1 = (const float*)d_in[3];
    const float* b1 = (const float*)d_in[4];
    const float* W3 = (const float*)d_in[5];
    const float* b3 = (const float*)d_in[6];
    const int* psrc = (const int*)d_in[7];
    const int* pdst = (const int*)d_in[8];
    float* out = (float*)d_out;

    const int nEdges = in_sizes[7];
    const int nNodesI = in_sizes[0] / 64;   // zi rows
    const int nNodesJ = in_sizes[1] / 64;   // zj rows
    const int nTiles = (nEdges + 31) / 32;
    const int nBlocks = (nTiles + TILES_PER_BLOCK - 1) / TILES_PER_BLOCK;

    const size_t bytesI = (size_t)nNodesI * 64;   // 1 byte per element
    const size_t bytesJ = (size_t)nNodesJ * 64;
    const bool useF8 = (ws_size >= bytesI + bytesJ);

    if (useF8) {
        unsigned char* zif8 = (unsigned char*)d_ws;
        unsigned char* zjf8 = (unsigned char*)d_ws + bytesI;
        const int nChunkPer = nNodesI * 64 / 8;
        hipLaunchKernelGGL(prep_fp8, dim3(2048), dim3(256), 0, stream,
                           zi, zj, (uint2*)zif8, (uint2*)zjf8, nChunkPer);
        hipLaunchKernelGGL((graphlp_mfma<true>), dim3(nBlocks), dim3(256), 0, stream,
                           zi, zj, zif8, zjf8, W1, b1, W3, b3, psrc, pdst,
                           out, nEdges, nTiles);
    } else {
        hipLaunchKernelGGL((graphlp_mfma<false>), dim3(nBlocks), dim3(256), 0, stream,
                           zi, zj, (const unsigned char*)nullptr, (const unsigned char*)nullptr,
                           W1, b1, W3, b3, psrc, pdst, out, nEdges, nTiles);
    }
}